// Round 2
// baseline (402.067 us; speedup 1.0000x reference)
//
#include <hip/hip_runtime.h>

// Problem constants
#define T_STEPS 8
#define NROW    42            // C*Dp = 3*14
#define BN      2688          // B*NROW = 64*42
#define H0      256
#define H1      128
#define NCLS    6
#define KFLAT   5376          // NROW*H1

// LDS column swizzle: +4 floats every 32 → stride-8 read groups land 2-way/bank
#define SW(r)   ((r) + ((r) >> 5) * 4)
#define LDR     140           // LDS row stride (floats), 16B-aligned (140*4=560)

// ---------------------------------------------------------------------------
// K1: avg-pool3d (2,2,2)/(2,2,2) VALID over (D=29,H=32,W=32) chunks.
// ---------------------------------------------------------------------------
__global__ __launch_bounds__(256) void pool_kernel(const float* __restrict__ x,
                                                   float* __restrict__ pr) {
    int idx = blockIdx.x * 256 + threadIdx.x;      // < 5,505,024
    int f   = idx & 255;
    int wp  = f & 15, hp = f >> 4;
    int rest = idx >> 8;                           // (t,b,c,dp), 21504 total
    int dp = rest % 14;
    int r2 = rest / 14;
    int c  = r2 % 3;
    int r3 = r2 / 3;
    int b  = r3 & 63;
    int t  = r3 >> 6;
    const float* base = x + ((long)b * 712704 + (long)c * 237568
                          + (long)(t * 29 + 2 * dp) * 1024
                          + (2 * hp) * 32 + 2 * wp);
    float2 v0 = *(const float2*)(base);
    float2 v1 = *(const float2*)(base + 32);
    float2 v2 = *(const float2*)(base + 1024);
    float2 v3 = *(const float2*)(base + 1056);
    float s = v0.x + v0.y + v1.x + v1.y + v2.x + v2.y + v3.x + v3.y;
    int m = t * BN + b * NROW + c * 14 + dp;
    pr[(long)m * 256 + f] = s * 0.125f;
}

// ---------------------------------------------------------------------------
// K2/K4: C[M x N] = A[M x K] * B[N x K]^T + bias.
// 128x128 tile, 256 threads, 8x8 micro-tile, K-chunk 16.
// LDS transposed [k][row] with SW swizzle (2 FLOP/LDS-byte -> VALU-bound).
// Per-output accumulation is k-ascending fmaf (bit-identical to round 1).
// ---------------------------------------------------------------------------
__global__ __launch_bounds__(256, 4) void gemm_abt(const float* __restrict__ A,
                                                   const float* __restrict__ B,
                                                   const float* __restrict__ bias,
                                                   float* __restrict__ C,
                                                   int N, int K) {
    __shared__ float At[16 * LDR];
    __shared__ float Bt[16 * LDR];
    int tid = threadIdx.x;
    int m0 = blockIdx.y * 128, n0 = blockIdx.x * 128;

    // staging map: row = tid>>1 (0..127), half = tid&1 picks k-octet
    int sr = tid >> 1, sq = tid & 1;
    int scol = SW(sr);
    const float* Ap = A + (long)(m0 + sr) * K + sq * 8;
    const float* Bp = B + (long)(n0 + sr) * K + sq * 8;

    // compute map: 16x16 thread grid, 8x8 micro
    int tm = tid & 15, tn = tid >> 4;
    int ca = SW(tm * 8);
    int cb = SW(tn * 8);

    float acc[8][8] = {};

    for (int k0 = 0; k0 < K; k0 += 16) {
        float4 a0 = *(const float4*)(Ap + k0);
        float4 a1 = *(const float4*)(Ap + k0 + 4);
        float4 b0 = *(const float4*)(Bp + k0);
        float4 b1 = *(const float4*)(Bp + k0 + 4);
        __syncthreads();
        int kb = sq * 8;
        At[(kb + 0) * LDR + scol] = a0.x; At[(kb + 1) * LDR + scol] = a0.y;
        At[(kb + 2) * LDR + scol] = a0.z; At[(kb + 3) * LDR + scol] = a0.w;
        At[(kb + 4) * LDR + scol] = a1.x; At[(kb + 5) * LDR + scol] = a1.y;
        At[(kb + 6) * LDR + scol] = a1.z; At[(kb + 7) * LDR + scol] = a1.w;
        Bt[(kb + 0) * LDR + scol] = b0.x; Bt[(kb + 1) * LDR + scol] = b0.y;
        Bt[(kb + 2) * LDR + scol] = b0.z; Bt[(kb + 3) * LDR + scol] = b0.w;
        Bt[(kb + 4) * LDR + scol] = b1.x; Bt[(kb + 5) * LDR + scol] = b1.y;
        Bt[(kb + 6) * LDR + scol] = b1.z; Bt[(kb + 7) * LDR + scol] = b1.w;
        __syncthreads();
#pragma unroll
        for (int k = 0; k < 16; ++k) {
            float4 av0 = *(const float4*)&At[k * LDR + ca];
            float4 av1 = *(const float4*)&At[k * LDR + ca + 4];
            float4 bv0 = *(const float4*)&Bt[k * LDR + cb];
            float4 bv1 = *(const float4*)&Bt[k * LDR + cb + 4];
            float am[8] = {av0.x, av0.y, av0.z, av0.w, av1.x, av1.y, av1.z, av1.w};
            float bn_[8] = {bv0.x, bv0.y, bv0.z, bv0.w, bv1.x, bv1.y, bv1.z, bv1.w};
#pragma unroll
            for (int i = 0; i < 8; ++i)
#pragma unroll
                for (int j = 0; j < 8; ++j)
                    acc[i][j] = fmaf(am[i], bn_[j], acc[i][j]);
        }
    }

#pragma unroll
    for (int i = 0; i < 8; ++i) {
        int row = m0 + tm * 8 + i;
        int col = n0 + tn * 8;
        float4 o0, o1;
        o0.x = acc[i][0] + bias[col + 0];
        o0.y = acc[i][1] + bias[col + 1];
        o0.z = acc[i][2] + bias[col + 2];
        o0.w = acc[i][3] + bias[col + 3];
        o1.x = acc[i][4] + bias[col + 4];
        o1.y = acc[i][5] + bias[col + 5];
        o1.z = acc[i][6] + bias[col + 6];
        o1.w = acc[i][7] + bias[col + 7];
        *(float4*)&C[(long)row * N + col]     = o0;
        *(float4*)&C[(long)row * N + col + 4] = o1;
    }
}

// ---------------------------------------------------------------------------
// K3/K5: LIF recurrence over t. F in {256,128}.
// ---------------------------------------------------------------------------
__global__ __launch_bounds__(256) void lif_kernel(const float* __restrict__ cur_all,
                                                  const float* __restrict__ beta,
                                                  const float* __restrict__ thr,
                                                  float* __restrict__ spk_all,
                                                  int F) {
    int j = blockIdx.x * 256 + threadIdx.x;   // < BN*F
    int h = j & (F - 1);
    float be = fminf(fmaxf(beta[h], 0.f), 1.f);
    float th = thr[h];
    float mem = 0.f;
    long stride = (long)BN * F;
#pragma unroll
    for (int t = 0; t < T_STEPS; ++t) {
        float cur = cur_all[t * stride + j];
        float reset = (mem > th) ? th : 0.f;
        mem = be * mem + cur - reset;
        spk_all[t * stride + j] = ((mem - th) > 0.f) ? 1.f : 0.f;
    }
}

// ---------------------------------------------------------------------------
// K6: cur_out[row=(t*64+b)][cls] = sum_f spkh[row][f]*W_out[cls][f] + b_out
// ---------------------------------------------------------------------------
__global__ __launch_bounds__(256) void out_gemm(const float* __restrict__ spkh,
                                                const float* __restrict__ W_out,
                                                const float* __restrict__ b_out,
                                                float* __restrict__ cur_out) {
    __shared__ float part[256][8];
    int row = blockIdx.x;                    // t*64 + b
    int tid = threadIdx.x;
    const float* a = spkh + (long)row * KFLAT;
    float acc[6] = {0.f, 0.f, 0.f, 0.f, 0.f, 0.f};
    for (int j = tid; j < KFLAT; j += 256) {
        float s = a[j];
#pragma unroll
        for (int c = 0; c < 6; ++c)
            acc[c] = fmaf(s, W_out[c * KFLAT + j], acc[c]);
    }
#pragma unroll
    for (int c = 0; c < 6; ++c) part[tid][c] = acc[c];
    __syncthreads();
    for (int off = 128; off > 0; off >>= 1) {
        if (tid < off) {
#pragma unroll
            for (int c = 0; c < 6; ++c) part[tid][c] += part[tid + off][c];
        }
        __syncthreads();
    }
    if (tid < 6) cur_out[row * 6 + tid] = part[0][tid] + b_out[tid];
}

// ---------------------------------------------------------------------------
// K7: output-layer LIF (threshold 1.0), writes spikes (8,64,6) to d_out
// ---------------------------------------------------------------------------
__global__ void lif_out_kernel(const float* __restrict__ cur_out,
                               const float* __restrict__ beta_out,
                               float* __restrict__ out) {
    int j = threadIdx.x;                     // < 384, j = b*6 + cls
    if (j >= 384) return;
    int cls = j % 6;
    float be = fminf(fmaxf(beta_out[cls], 0.f), 1.f);
    float mem = 0.f;
#pragma unroll
    for (int t = 0; t < T_STEPS; ++t) {
        float cur = cur_out[t * 384 + j];
        float reset = (mem > 1.f) ? 1.f : 0.f;
        mem = be * mem + cur - reset;
        out[t * 384 + j] = ((mem - 1.f) > 0.f) ? 1.f : 0.f;
    }
}

extern "C" void kernel_launch(void* const* d_in, const int* in_sizes, int n_in,
                              void* d_out, int out_size, void* d_ws, size_t ws_size,
                              hipStream_t stream) {
    (void)in_sizes; (void)n_in; (void)out_size; (void)ws_size;
    const float* x        = (const float*)d_in[0];
    const float* W_in     = (const float*)d_in[1];
    const float* b_in     = (const float*)d_in[2];
    const float* W_hid    = (const float*)d_in[3];
    const float* b_hid    = (const float*)d_in[4];
    const float* W_out    = (const float*)d_in[5];
    const float* b_out    = (const float*)d_in[6];
    const float* beta_in  = (const float*)d_in[7];
    const float* thr_in   = (const float*)d_in[8];
    const float* beta_hid = (const float*)d_in[9];
    const float* thr_hid  = (const float*)d_in[10];
    const float* beta_out = (const float*)d_in[11];
    float* out = (float*)d_out;

    float* buf0 = (float*)d_ws;            // 5,505,024 floats
    float* buf1 = buf0 + 5505024;          // 5,505,024 floats
    float* curo = buf1 + 5505024;          // 3,072 floats

    // 1. pool: x -> pr (buf0)
    pool_kernel<<<21504, 256, 0, stream>>>(x, buf0);
    // 2. cur_in_all = pr @ W_in^T + b_in  (buf0 -> buf1), M=21504,N=256,K=256
    gemm_abt<<<dim3(2, 168), 256, 0, stream>>>(buf0, W_in, b_in, buf1, 256, 256);
    // 3. LIF_in: buf1 -> spk_in_all (buf0)
    lif_kernel<<<2688, 256, 0, stream>>>(buf1, beta_in, thr_in, buf0, 256);
    // 4. cur_hid_all = spk_in @ W_hid^T + b_hid (buf0 -> buf1), N=128
    gemm_abt<<<dim3(1, 168), 256, 0, stream>>>(buf0, W_hid, b_hid, buf1, 128, 256);
    // 5. LIF_hid: buf1 -> spk_hid_all (buf0)
    lif_kernel<<<1344, 256, 0, stream>>>(buf1, beta_hid, thr_hid, buf0, 128);
    // 6. cur_out_all: (t,b) rows x 5376 -> 6
    out_gemm<<<512, 256, 0, stream>>>(buf0, W_out, b_out, curo);
    // 7. output LIF -> d_out
    lif_out_kernel<<<1, 384, 0, stream>>>(curo, beta_out, out);
}

// Round 3
// 388.041 us; speedup vs baseline: 1.0361x; 1.0361x over previous
//
#include <hip/hip_runtime.h>

// Problem constants
#define T_STEPS 8
#define NROW    42            // C*Dp = 3*14
#define BN      2688          // B*NROW = 64*42
#define H0      256
#define H1      128
#define NCLS    6
#define KFLAT   5376          // NROW*H1

// Row layout is t-minor: m' = (b*42 + c*14 + dp)*8 + t.
// A 128-row GEMM tile therefore holds 16 neuron-groups x all 8 timesteps,
// and each thread's 8x8 micro-tile holds one group's full time axis ->
// the LIF recurrence runs in the GEMM epilogue registers (bit-identical
// to a separate LIF kernel: same fmaf sequence on the same values).

// LDS column swizzle: +4 floats every 32 -> stride-8 read groups land 2-way/bank
#define SW(r)   ((r) + ((r) >> 5) * 4)
#define LDR     140           // LDS row stride (floats), 16B-aligned (140*4=560)

// ---------------------------------------------------------------------------
// K1: avg-pool3d (2,2,2)/(2,2,2) VALID; writes pr in t-minor row layout.
// ---------------------------------------------------------------------------
__global__ __launch_bounds__(256) void pool_kernel(const float* __restrict__ x,
                                                   float* __restrict__ pr) {
    int idx = blockIdx.x * 256 + threadIdx.x;      // < 5,505,024
    int f   = idx & 255;
    int wp  = f & 15, hp = f >> 4;
    int rest = idx >> 8;                           // (t,b,c,dp), 21504 total
    int dp = rest % 14;
    int r2 = rest / 14;
    int c  = r2 % 3;
    int r3 = r2 / 3;
    int b  = r3 & 63;
    int t  = r3 >> 6;
    const float* base = x + ((long)b * 712704 + (long)c * 237568
                          + (long)(t * 29 + 2 * dp) * 1024
                          + (2 * hp) * 32 + 2 * wp);
    float2 v0 = *(const float2*)(base);
    float2 v1 = *(const float2*)(base + 32);
    float2 v2 = *(const float2*)(base + 1024);
    float2 v3 = *(const float2*)(base + 1056);
    float s = v0.x + v0.y + v1.x + v1.y + v2.x + v2.y + v3.x + v3.y;
    int m = (b * NROW + c * 14 + dp) * 8 + t;      // t-minor
    pr[(long)m * 256 + f] = s * 0.125f;
}

// ---------------------------------------------------------------------------
// K2/K3: fused  C = A[M x K] * B[N x K]^T + bias  ->  LIF  ->  spikes.
// 128x128 tile, 256 threads, 8x8 micro-tile, K-chunk 16.
// launch_bounds(256,2): 256-VGPR cap so acc[8][8] does NOT spill.
// ---------------------------------------------------------------------------
__global__ __launch_bounds__(256, 2) void gemm_lif(const float* __restrict__ A,
                                                   const float* __restrict__ B,
                                                   const float* __restrict__ bias,
                                                   const float* __restrict__ beta,
                                                   const float* __restrict__ thr,
                                                   float* __restrict__ spk,
                                                   int N, int K) {
    __shared__ float At[16 * LDR];
    __shared__ float Bt[16 * LDR];
    int tid = threadIdx.x;
    int m0 = blockIdx.y * 128, n0 = blockIdx.x * 128;

    // staging map: row = tid>>1 (0..127), half = tid&1 picks k-octet
    int sr = tid >> 1, sq = tid & 1;
    int scol = SW(sr);
    const float* Ap = A + (long)(m0 + sr) * K + sq * 8;
    const float* Bp = B + (long)(n0 + sr) * K + sq * 8;

    // compute map: 16x16 thread grid, 8x8 micro-tile
    int tm = tid & 15, tn = tid >> 4;
    int ca = SW(tm * 8);
    int cb = SW(tn * 8);

    float acc[8][8] = {};

    for (int k0 = 0; k0 < K; k0 += 16) {
        float4 a0 = *(const float4*)(Ap + k0);
        float4 a1 = *(const float4*)(Ap + k0 + 4);
        float4 b0 = *(const float4*)(Bp + k0);
        float4 b1 = *(const float4*)(Bp + k0 + 4);
        __syncthreads();
        int kb = sq * 8;
        At[(kb + 0) * LDR + scol] = a0.x; At[(kb + 1) * LDR + scol] = a0.y;
        At[(kb + 2) * LDR + scol] = a0.z; At[(kb + 3) * LDR + scol] = a0.w;
        At[(kb + 4) * LDR + scol] = a1.x; At[(kb + 5) * LDR + scol] = a1.y;
        At[(kb + 6) * LDR + scol] = a1.z; At[(kb + 7) * LDR + scol] = a1.w;
        Bt[(kb + 0) * LDR + scol] = b0.x; Bt[(kb + 1) * LDR + scol] = b0.y;
        Bt[(kb + 2) * LDR + scol] = b0.z; Bt[(kb + 3) * LDR + scol] = b0.w;
        Bt[(kb + 4) * LDR + scol] = b1.x; Bt[(kb + 5) * LDR + scol] = b1.y;
        Bt[(kb + 6) * LDR + scol] = b1.z; Bt[(kb + 7) * LDR + scol] = b1.w;
        __syncthreads();
#pragma unroll
        for (int k = 0; k < 16; ++k) {
            float4 av0 = *(const float4*)&At[k * LDR + ca];
            float4 av1 = *(const float4*)&At[k * LDR + ca + 4];
            float4 bv0 = *(const float4*)&Bt[k * LDR + cb];
            float4 bv1 = *(const float4*)&Bt[k * LDR + cb + 4];
            float am[8] = {av0.x, av0.y, av0.z, av0.w, av1.x, av1.y, av1.z, av1.w};
            float bn_[8] = {bv0.x, bv0.y, bv0.z, bv0.w, bv1.x, bv1.y, bv1.z, bv1.w};
#pragma unroll
            for (int i = 0; i < 8; ++i)
#pragma unroll
                for (int j = 0; j < 8; ++j)
                    acc[i][j] = fmaf(am[i], bn_[j], acc[i][j]);
        }
    }

    // --- LIF epilogue: micro-tile row i == timestep t of neuron-group jgrp ---
#pragma unroll
    for (int c = 0; c < 8; ++c) {
        int h = n0 + tn * 8 + c;
        float be = fminf(fmaxf(beta[h], 0.f), 1.f);
        float th = thr[h];
        float bi = bias[h];
        float mem = 0.f;
#pragma unroll
        for (int t = 0; t < T_STEPS; ++t) {
            float cur = acc[t][c] + bi;
            float reset = (mem > th) ? th : 0.f;
            mem = be * mem + cur - reset;
            acc[t][c] = ((mem - th) > 0.f) ? 1.f : 0.f;
        }
    }
    int rbase = m0 + tm * 8;                 // = jgrp*8
#pragma unroll
    for (int t = 0; t < T_STEPS; ++t) {
        long row = rbase + t;
        int col = n0 + tn * 8;
        float4 o0 = {acc[t][0], acc[t][1], acc[t][2], acc[t][3]};
        float4 o1 = {acc[t][4], acc[t][5], acc[t][6], acc[t][7]};
        *(float4*)&spk[row * N + col]     = o0;
        *(float4*)&spk[row * N + col + 4] = o1;
    }
}

// ---------------------------------------------------------------------------
// K4: cur_out[row=(t*64+b)][cls], reading spk_hid in t-minor layout.
// ---------------------------------------------------------------------------
__global__ __launch_bounds__(256) void out_gemm(const float* __restrict__ spkh,
                                                const float* __restrict__ W_out,
                                                const float* __restrict__ b_out,
                                                float* __restrict__ cur_out) {
    __shared__ float part[256][8];
    int row = blockIdx.x;                    // t*64 + b
    int t = row >> 6, b = row & 63;
    int tid = threadIdx.x;
    float acc[6] = {0.f, 0.f, 0.f, 0.f, 0.f, 0.f};
    for (int j = tid; j < KFLAT; j += 256) {
        int n = j >> 7, h = j & 127;
        float s = spkh[((long)(b * NROW + n) * 8 + t) * 128 + h];
#pragma unroll
        for (int c = 0; c < 6; ++c)
            acc[c] = fmaf(s, W_out[c * KFLAT + j], acc[c]);
    }
#pragma unroll
    for (int c = 0; c < 6; ++c) part[tid][c] = acc[c];
    __syncthreads();
    for (int off = 128; off > 0; off >>= 1) {
        if (tid < off) {
#pragma unroll
            for (int c = 0; c < 6; ++c) part[tid][c] += part[tid + off][c];
        }
        __syncthreads();
    }
    if (tid < 6) cur_out[row * 6 + tid] = part[0][tid] + b_out[tid];
}

// ---------------------------------------------------------------------------
// K5: output-layer LIF (threshold 1.0), writes spikes (8,64,6) to d_out
// ---------------------------------------------------------------------------
__global__ void lif_out_kernel(const float* __restrict__ cur_out,
                               const float* __restrict__ beta_out,
                               float* __restrict__ out) {
    int j = threadIdx.x;                     // < 384, j = b*6 + cls
    if (j >= 384) return;
    int cls = j % 6;
    float be = fminf(fmaxf(beta_out[cls], 0.f), 1.f);
    float mem = 0.f;
#pragma unroll
    for (int t = 0; t < T_STEPS; ++t) {
        float cur = cur_out[t * 384 + j];
        float reset = (mem > 1.f) ? 1.f : 0.f;
        mem = be * mem + cur - reset;
        out[t * 384 + j] = ((mem - 1.f) > 0.f) ? 1.f : 0.f;
    }
}

extern "C" void kernel_launch(void* const* d_in, const int* in_sizes, int n_in,
                              void* d_out, int out_size, void* d_ws, size_t ws_size,
                              hipStream_t stream) {
    (void)in_sizes; (void)n_in; (void)out_size; (void)ws_size;
    const float* x        = (const float*)d_in[0];
    const float* W_in     = (const float*)d_in[1];
    const float* b_in     = (const float*)d_in[2];
    const float* W_hid    = (const float*)d_in[3];
    const float* b_hid    = (const float*)d_in[4];
    const float* W_out    = (const float*)d_in[5];
    const float* b_out    = (const float*)d_in[6];
    const float* beta_in  = (const float*)d_in[7];
    const float* thr_in   = (const float*)d_in[8];
    const float* beta_hid = (const float*)d_in[9];
    const float* thr_hid  = (const float*)d_in[10];
    const float* beta_out = (const float*)d_in[11];
    float* out = (float*)d_out;

    float* buf0 = (float*)d_ws;            // 5,505,024 floats
    float* buf1 = buf0 + 5505024;          // 5,505,024 floats
    float* curo = buf1 + 5505024;          // 3,072 floats

    // 1. pool: x -> pr (buf0), t-minor rows
    pool_kernel<<<21504, 256, 0, stream>>>(x, buf0);
    // 2. spk_in = LIF(pr @ W_in^T + b_in)  (buf0 -> buf1), M=21504,N=256,K=256
    gemm_lif<<<dim3(2, 168), 256, 0, stream>>>(buf0, W_in, b_in, beta_in, thr_in,
                                               buf1, 256, 256);
    // 3. spk_hid = LIF(spk_in @ W_hid^T + b_hid) (buf1 -> buf0), N=128
    gemm_lif<<<dim3(1, 168), 256, 0, stream>>>(buf1, W_hid, b_hid, beta_hid, thr_hid,
                                               buf0, 128, 256);
    // 4. cur_out_all: (t,b) rows x 5376 -> 6
    out_gemm<<<512, 256, 0, stream>>>(buf0, W_out, b_out, curo);
    // 5. output LIF -> d_out
    lif_out_kernel<<<1, 384, 0, stream>>>(curo, beta_out, out);
}

// Round 4
// 355.771 us; speedup vs baseline: 1.1301x; 1.0907x over previous
//
#include <hip/hip_runtime.h>

// Problem constants
#define T_STEPS 8
#define NROW    42            // C*Dp = 3*14
#define BN      2688          // B*NROW = 64*42
#define H0      256
#define H1      128
#define KFLAT   5376          // NROW*H1

// Row layout is t-minor: m = (b*42 + c*14 + dp)*8 + t, so each thread's
// micro-tile rows are one neuron-group's full time axis and the LIF
// recurrence runs in the GEMM epilogue registers (bit-identical chain).

// LDS column swizzle: +4 floats every 32 -> stride-8/4 read groups conflict-free
#define SWA(r)  ((r) + ((r) >> 5) * 4)

// ---------------------------------------------------------------------------
// K1: FUSED avg-pool3d -> (A @ W_in^T + b_in) -> LIF -> spk_in.
// Tile 64 rows x 256 cols (full N), 512 threads, 8x4 micro-tile.
// A-tile is pooled from x on the fly during staging: the 180 MB HBM x-read
// overlaps the FMA work instead of running as a separate serial kernel.
// Pooling add order and k-ascending fmaf order match the reference bitwise.
// ---------------------------------------------------------------------------
__global__ __launch_bounds__(512, 4) void pool_gemm_lif(
        const float* __restrict__ x,
        const float* __restrict__ B,      // W_in [256][256]
        const float* __restrict__ bias,
        const float* __restrict__ beta,
        const float* __restrict__ thr,
        float* __restrict__ spk) {        // [21504][256], t-minor rows
    __shared__ float At[16 * 68];         // [k][m], swizzled cols
    __shared__ float Bt[16 * 284];        // [k][n], swizzled cols
    int tid = threadIdx.x;
    int gbase = blockIdx.x * 8;           // 8 neuron-groups per block

    // ---- A staging map: 2 pooled elements per thread per k-chunk ----
    int wp = tid & 15;                    // k-within-chunk == wp
    int q  = tid >> 4;                    // 0..31
    const float* xb0;
    const float* xb1;
    int mloc0 = q * 2, mloc1 = q * 2 + 1;
    {
        int g = gbase + (mloc0 >> 3);
        int t = mloc0 & 7;
        int b = g / 42, r = g - b * 42;
        int c = r / 14, dp = r - c * 14;
        xb0 = x + ((long)b * 712704 + (long)c * 237568
                + (long)(t * 29 + 2 * dp) * 1024 + 2 * wp);
    }
    {
        int g = gbase + (mloc1 >> 3);
        int t = mloc1 & 7;
        int b = g / 42, r = g - b * 42;
        int c = r / 14, dp = r - c * 14;
        xb1 = x + ((long)b * 712704 + (long)c * 237568
                + (long)(t * 29 + 2 * dp) * 1024 + 2 * wp);
    }
    int acol0 = SWA(mloc0), acol1 = SWA(mloc1);

    // ---- B staging map ----
    int bn0 = tid >> 1;                   // 0..255 (row of W_in)
    int bq  = tid & 1;                    // k-octet
    const float* Bp = B + (long)bn0 * 256 + bq * 8;
    int bcol = SWA(bn0);

    // ---- compute map: 8 groups x 64 col-quads ----
    int tm = tid & 7, tn = tid >> 3;      // tn 0..63
    int ca = SWA(tm * 8);
    int cb = SWA(tn * 4);

    float acc[8][4] = {};

    for (int k0 = 0; k0 < 256; k0 += 16) {
        int hp = k0 >> 4;
        const float* p0 = xb0 + hp * 64;
        const float* p1 = xb1 + hp * 64;
        float2 a00 = *(const float2*)(p0);
        float2 a01 = *(const float2*)(p0 + 32);
        float2 a02 = *(const float2*)(p0 + 1024);
        float2 a03 = *(const float2*)(p0 + 1056);
        float2 a10 = *(const float2*)(p1);
        float2 a11 = *(const float2*)(p1 + 32);
        float2 a12 = *(const float2*)(p1 + 1024);
        float2 a13 = *(const float2*)(p1 + 1056);
        float4 w0 = *(const float4*)(Bp + k0);
        float4 w1 = *(const float4*)(Bp + k0 + 4);
        __syncthreads();
        // pooled values, exact reference add order
        float s0 = a00.x + a00.y + a01.x + a01.y + a02.x + a02.y + a03.x + a03.y;
        float s1 = a10.x + a10.y + a11.x + a11.y + a12.x + a12.y + a13.x + a13.y;
        At[wp * 68 + acol0] = s0 * 0.125f;
        At[wp * 68 + acol1] = s1 * 0.125f;
        int kb = bq * 8;
        Bt[(kb + 0) * 284 + bcol] = w0.x; Bt[(kb + 1) * 284 + bcol] = w0.y;
        Bt[(kb + 2) * 284 + bcol] = w0.z; Bt[(kb + 3) * 284 + bcol] = w0.w;
        Bt[(kb + 4) * 284 + bcol] = w1.x; Bt[(kb + 5) * 284 + bcol] = w1.y;
        Bt[(kb + 6) * 284 + bcol] = w1.z; Bt[(kb + 7) * 284 + bcol] = w1.w;
        __syncthreads();
#pragma unroll
        for (int k = 0; k < 16; ++k) {
            float4 av0 = *(const float4*)&At[k * 68 + ca];
            float4 av1 = *(const float4*)&At[k * 68 + ca + 4];
            float4 bv  = *(const float4*)&Bt[k * 284 + cb];
            float am[8] = {av0.x, av0.y, av0.z, av0.w, av1.x, av1.y, av1.z, av1.w};
            float bb[4] = {bv.x, bv.y, bv.z, bv.w};
#pragma unroll
            for (int i = 0; i < 8; ++i)
#pragma unroll
                for (int j = 0; j < 4; ++j)
                    acc[i][j] = fmaf(am[i], bb[j], acc[i][j]);
        }
    }

    // ---- LIF epilogue: micro-tile row i == timestep t of group tm ----
#pragma unroll
    for (int j = 0; j < 4; ++j) {
        int h = tn * 4 + j;
        float be = fminf(fmaxf(beta[h], 0.f), 1.f);
        float th = thr[h];
        float bi = bias[h];
        float mem = 0.f;
#pragma unroll
        for (int t = 0; t < T_STEPS; ++t) {
            float cur = acc[t][j] + bi;
            float reset = (mem > th) ? th : 0.f;
            mem = be * mem + cur - reset;
            acc[t][j] = ((mem - th) > 0.f) ? 1.f : 0.f;
        }
    }
    int rbase = blockIdx.x * 64 + tm * 8;
#pragma unroll
    for (int t = 0; t < T_STEPS; ++t) {
        float4 o = {acc[t][0], acc[t][1], acc[t][2], acc[t][3]};
        *(float4*)&spk[(long)(rbase + t) * 256 + tn * 4] = o;
    }
}

// ---------------------------------------------------------------------------
// K2: fused  spk_hid = LIF(spk_in @ W_hid^T + b_hid).
// Tile 64 rows x 128 cols, 256 threads, 8x4 micro-tile, 336 blocks.
// ---------------------------------------------------------------------------
__global__ __launch_bounds__(256, 4) void gemm_lif64(
        const float* __restrict__ A,      // [21504][256]
        const float* __restrict__ B,      // W_hid [128][256]
        const float* __restrict__ bias,
        const float* __restrict__ beta,
        const float* __restrict__ thr,
        float* __restrict__ spk) {        // [21504][128]
    __shared__ float At[16 * 68];
    __shared__ float Bt[16 * 140];
    int tid = threadIdx.x;
    int m0 = blockIdx.x * 64;

    int sr = tid >> 2, sq = tid & 3;      // A stage: 64 rows x 4 k-quads
    const float* Ap = A + (long)(m0 + sr) * 256 + sq * 4;
    int acolS = SWA(sr);

    int br = tid >> 1, bq = tid & 1;      // B stage: 128 rows x 2 k-octets
    const float* Bp = B + (long)br * 256 + bq * 8;
    int bcolS = SWA(br);

    int tm = tid & 7, tn = tid >> 3;      // tn 0..31
    int ca = SWA(tm * 8);
    int cb = SWA(tn * 4);

    float acc[8][4] = {};

    for (int k0 = 0; k0 < 256; k0 += 16) {
        float4 a  = *(const float4*)(Ap + k0);
        float4 w0 = *(const float4*)(Bp + k0);
        float4 w1 = *(const float4*)(Bp + k0 + 4);
        __syncthreads();
        int ka = sq * 4;
        At[(ka + 0) * 68 + acolS] = a.x; At[(ka + 1) * 68 + acolS] = a.y;
        At[(ka + 2) * 68 + acolS] = a.z; At[(ka + 3) * 68 + acolS] = a.w;
        int kb = bq * 8;
        Bt[(kb + 0) * 140 + bcolS] = w0.x; Bt[(kb + 1) * 140 + bcolS] = w0.y;
        Bt[(kb + 2) * 140 + bcolS] = w0.z; Bt[(kb + 3) * 140 + bcolS] = w0.w;
        Bt[(kb + 4) * 140 + bcolS] = w1.x; Bt[(kb + 5) * 140 + bcolS] = w1.y;
        Bt[(kb + 6) * 140 + bcolS] = w1.z; Bt[(kb + 7) * 140 + bcolS] = w1.w;
        __syncthreads();
#pragma unroll
        for (int k = 0; k < 16; ++k) {
            float4 av0 = *(const float4*)&At[k * 68 + ca];
            float4 av1 = *(const float4*)&At[k * 68 + ca + 4];
            float4 bv  = *(const float4*)&Bt[k * 140 + cb];
            float am[8] = {av0.x, av0.y, av0.z, av0.w, av1.x, av1.y, av1.z, av1.w};
            float bb[4] = {bv.x, bv.y, bv.z, bv.w};
#pragma unroll
            for (int i = 0; i < 8; ++i)
#pragma unroll
                for (int j = 0; j < 4; ++j)
                    acc[i][j] = fmaf(am[i], bb[j], acc[i][j]);
        }
    }

#pragma unroll
    for (int j = 0; j < 4; ++j) {
        int h = tn * 4 + j;
        float be = fminf(fmaxf(beta[h], 0.f), 1.f);
        float th = thr[h];
        float bi = bias[h];
        float mem = 0.f;
#pragma unroll
        for (int t = 0; t < T_STEPS; ++t) {
            float cur = acc[t][j] + bi;
            float reset = (mem > th) ? th : 0.f;
            mem = be * mem + cur - reset;
            acc[t][j] = ((mem - th) > 0.f) ? 1.f : 0.f;
        }
    }
    int rbase = m0 + tm * 8;
#pragma unroll
    for (int t = 0; t < T_STEPS; ++t) {
        float4 o = {acc[t][0], acc[t][1], acc[t][2], acc[t][3]};
        *(float4*)&spk[(long)(rbase + t) * 128 + tn * 4] = o;
    }
}

// ---------------------------------------------------------------------------
// K3: cur_out[row=(t*64+b)][cls], reading spk_hid in t-minor layout.
// (unchanged from round 3 — preserves the passing reduction order)
// ---------------------------------------------------------------------------
__global__ __launch_bounds__(256) void out_gemm(const float* __restrict__ spkh,
                                                const float* __restrict__ W_out,
                                                const float* __restrict__ b_out,
                                                float* __restrict__ cur_out) {
    __shared__ float part[256][8];
    int row = blockIdx.x;                    // t*64 + b
    int t = row >> 6, b = row & 63;
    int tid = threadIdx.x;
    float acc[6] = {0.f, 0.f, 0.f, 0.f, 0.f, 0.f};
    for (int j = tid; j < KFLAT; j += 256) {
        int n = j >> 7, h = j & 127;
        float s = spkh[((long)(b * NROW + n) * 8 + t) * 128 + h];
#pragma unroll
        for (int c = 0; c < 6; ++c)
            acc[c] = fmaf(s, W_out[c * KFLAT + j], acc[c]);
    }
#pragma unroll
    for (int c = 0; c < 6; ++c) part[tid][c] = acc[c];
    __syncthreads();
    for (int off = 128; off > 0; off >>= 1) {
        if (tid < off) {
#pragma unroll
            for (int c = 0; c < 6; ++c) part[tid][c] += part[tid + off][c];
        }
        __syncthreads();
    }
    if (tid < 6) cur_out[row * 6 + tid] = part[0][tid] + b_out[tid];
}

// ---------------------------------------------------------------------------
// K4: output-layer LIF (threshold 1.0), writes spikes (8,64,6) to d_out
// ---------------------------------------------------------------------------
__global__ void lif_out_kernel(const float* __restrict__ cur_out,
                               const float* __restrict__ beta_out,
                               float* __restrict__ out) {
    int j = threadIdx.x;                     // < 384, j = b*6 + cls
    if (j >= 384) return;
    int cls = j % 6;
    float be = fminf(fmaxf(beta_out[cls], 0.f), 1.f);
    float mem = 0.f;
#pragma unroll
    for (int t = 0; t < T_STEPS; ++t) {
        float cur = cur_out[t * 384 + j];
        float reset = (mem > 1.f) ? 1.f : 0.f;
        mem = be * mem + cur - reset;
        out[t * 384 + j] = ((mem - 1.f) > 0.f) ? 1.f : 0.f;
    }
}

extern "C" void kernel_launch(void* const* d_in, const int* in_sizes, int n_in,
                              void* d_out, int out_size, void* d_ws, size_t ws_size,
                              hipStream_t stream) {
    (void)in_sizes; (void)n_in; (void)out_size; (void)ws_size;
    const float* x        = (const float*)d_in[0];
    const float* W_in     = (const float*)d_in[1];
    const float* b_in     = (const float*)d_in[2];
    const float* W_hid    = (const float*)d_in[3];
    const float* b_hid    = (const float*)d_in[4];
    const float* W_out    = (const float*)d_in[5];
    const float* b_out    = (const float*)d_in[6];
    const float* beta_in  = (const float*)d_in[7];
    const float* thr_in   = (const float*)d_in[8];
    const float* beta_hid = (const float*)d_in[9];
    const float* thr_hid  = (const float*)d_in[10];
    const float* beta_out = (const float*)d_in[11];
    float* out = (float*)d_out;

    float* buf0 = (float*)d_ws;            // spk_hid: 21504*128 floats
    float* buf1 = buf0 + 5505024;          // spk_in:  21504*256 floats
    float* curo = buf1 + 5505024;          // 3,072 floats

    // 1. fused pool + fc_in + LIF: x -> spk_in (buf1), 336 blocks x 512 thr
    pool_gemm_lif<<<336, 512, 0, stream>>>(x, W_in, b_in, beta_in, thr_in, buf1);
    // 2. fused fc_hid + LIF: spk_in -> spk_hid (buf0), 336 blocks x 256 thr
    gemm_lif64<<<336, 256, 0, stream>>>(buf1, W_hid, b_hid, beta_hid, thr_hid, buf0);
    // 3. cur_out_all: (t,b) rows x 5376 -> 6
    out_gemm<<<512, 256, 0, stream>>>(buf0, W_out, b_out, curo);
    // 4. output LIF -> d_out
    lif_out_kernel<<<1, 384, 0, stream>>>(curo, beta_out, out);
}